// Round 1
// baseline (1348.371 us; speedup 1.0000x reference)
//
#include <hip/hip_runtime.h>
#include <math.h>

#define N_ 1024
#define L_ 2048
#define D_ 128
#define THREADS 256
#define GROUPS (THREADS / 32)   // 8 row-groups of 32 lanes

// out[n] = sum_l softmax_l(X[n,l]·q[n]) * (X[n,l]·v),  q[n] = z[n] @ W
// Single streaming pass over X with online softmax. Memory-bound: 1.07 GB read.
__global__ __launch_bounds__(THREADS) void attw_fused(
    const float* __restrict__ X,   // [N, L, D] input_seq
    const float* __restrict__ Z,   // [N, D]    cross_input
    const float* __restrict__ W,   // [D, D]
    const float* __restrict__ V,   // [D]
    float* __restrict__ out)       // [N]
{
    __shared__ float s_q[D_];
    __shared__ float s_v[D_];
    __shared__ float red_m[GROUPS], red_se[GROUPS], red_st[GROUPS];

    const int n = blockIdx.x;
    const int t = threadIdx.x;

    // q[d] = sum_e Z[n,e] * W[e,d]   (W rows read coalesced; W is L2/L3-hot)
    if (t < D_) {
        float acc = 0.f;
        const float* z = Z + n * D_;
        #pragma unroll 8
        for (int e = 0; e < D_; ++e)
            acc += z[e] * W[e * D_ + t];
        s_q[t] = acc;
    } else {
        // threads 128..255 stage v
        s_v[t - D_] = V[t - D_];
    }
    __syncthreads();

    const int g    = t >> 5;   // group 0..7 (row owner)
    const int lane = t & 31;   // 0..31 within group
    const float4 q4 = ((const float4*)s_q)[lane];
    const float4 v4 = ((const float4*)s_v)[lane];

    float m = -3.0e38f, se = 0.f, st = 0.f;

    const float4* Xrow = (const float4*)(X + (size_t)n * L_ * D_);
    // row l spans float4 indices [l*32, l*32+32); block reads 8 rows = 4 KB
    // contiguous per iteration (fully coalesced).

    #pragma unroll 4
    for (int l = g; l < L_; l += GROUPS) {
        const float4 x = Xrow[l * 32 + lane];
        float s  = x.x * q4.x + x.y * q4.y + x.z * q4.z + x.w * q4.w;
        float tv = x.x * v4.x + x.y * v4.y + x.z * v4.z + x.w * v4.w;
        // butterfly reduce across the 32-lane group (all lanes end with sum)
        #pragma unroll
        for (int mask = 16; mask > 0; mask >>= 1) {
            s  += __shfl_xor(s,  mask, 32);
            tv += __shfl_xor(tv, mask, 32);
        }
        // online softmax update (redundant across the 32 lanes — cheap)
        const float mnew  = fmaxf(m, s);
        const float scale = __expf(m - mnew);
        const float e     = __expf(s - mnew);
        se = se * scale + e;
        st = st * scale + e * tv;
        m  = mnew;
    }

    if (lane == 0) { red_m[g] = m; red_se[g] = se; red_st[g] = st; }
    __syncthreads();

    if (t == 0) {
        float M = red_m[0], SE = red_se[0], ST = red_st[0];
        #pragma unroll
        for (int i = 1; i < GROUPS; ++i) {
            const float m2  = red_m[i];
            const float Mn  = fmaxf(M, m2);
            const float sc1 = __expf(M - Mn);
            const float sc2 = __expf(m2 - Mn);
            SE = SE * sc1 + red_se[i] * sc2;
            ST = ST * sc1 + red_st[i] * sc2;
            M  = Mn;
        }
        out[n] = ST / SE;
    }
}

extern "C" void kernel_launch(void* const* d_in, const int* in_sizes, int n_in,
                              void* d_out, int out_size, void* d_ws, size_t ws_size,
                              hipStream_t stream) {
    const float* X = (const float*)d_in[0];  // input_seq [1024,2048,128]
    const float* Z = (const float*)d_in[1];  // cross_input [1024,128]
    const float* W = (const float*)d_in[2];  // W [128,128]
    const float* V = (const float*)d_in[3];  // v [128]
    float* out = (float*)d_out;              // [1024,1] fp32

    attw_fused<<<N_, THREADS, 0, stream>>>(X, Z, W, V, out);
}

// Round 2
// 1328.389 us; speedup vs baseline: 1.0150x; 1.0150x over previous
//
#include <hip/hip_runtime.h>
#include <math.h>

#define N_ 1024
#define L_ 2048
#define D_ 128
#define THREADS 256
#define GROUPS (THREADS / 32)     // 8 row-groups of 32 lanes per block
#define CHUNKS 8                  // L split into 8 chunks of 256 rows
#define CHUNK_ROWS (L_ / CHUNKS)  // 256

// ---------------------------------------------------------------------------
// Stage 0: Q[n,d] = sum_e Z[n,e] * W[e,d]   (tiny: 33 MFLOP, W is L2-hot)
// ---------------------------------------------------------------------------
__global__ __launch_bounds__(D_) void attw_q(
    const float* __restrict__ Z, const float* __restrict__ W,
    float* __restrict__ Q)
{
    const int n = blockIdx.x;
    const int d = threadIdx.x;
    const float* z = Z + n * D_;
    float acc = 0.f;
    #pragma unroll 8
    for (int e = 0; e < D_; ++e)
        acc += z[e] * W[e * D_ + d];   // W row coalesced; z[e] scalar broadcast
    Q[n * D_ + d] = acc;
}

// ---------------------------------------------------------------------------
// Stage 1: per-(n,chunk) online-softmax partials.
// Grid (CHUNKS, N) = 8192 blocks -> 32 blocks/CU queued: enough TLP to cover
// HBM latency + the shfl-reduce chain (the round-1 kernel had only 4/CU).
// Each 32-lane group owns a row: float4/lane, butterfly dot-reduce, online
// softmax update of (m, se, st). Partial written as float4 to d_ws.
// ---------------------------------------------------------------------------
__global__ __launch_bounds__(THREADS) void attw_partial(
    const float* __restrict__ X,   // [N, L, D]
    const float* __restrict__ Q,   // [N, D]
    const float* __restrict__ V,   // [D]
    float4* __restrict__ P)        // [N*CHUNKS] (m, se, st, -)
{
    const int c = blockIdx.x;
    const int n = blockIdx.y;
    const int t = threadIdx.x;
    const int g    = t >> 5;
    const int lane = t & 31;

    const float4 q4 = ((const float4*)(Q + n * D_))[lane];
    const float4 v4 = ((const float4*)V)[lane];

    float m = -3.0e38f, se = 0.f, st = 0.f;

    const float4* Xrow = (const float4*)(X + (size_t)n * L_ * D_);
    const int l0 = c * CHUNK_ROWS;

    #pragma unroll 4
    for (int l = l0 + g; l < l0 + CHUNK_ROWS; l += GROUPS) {
        const float4 x = Xrow[l * 32 + lane];   // 1 KB contiguous per wave
        float s  = x.x * q4.x + x.y * q4.y + x.z * q4.z + x.w * q4.w;
        float tv = x.x * v4.x + x.y * v4.y + x.z * v4.z + x.w * v4.w;
        #pragma unroll
        for (int mask = 16; mask > 0; mask >>= 1) {
            s  += __shfl_xor(s,  mask, 32);
            tv += __shfl_xor(tv, mask, 32);
        }
        const float mnew  = fmaxf(m, s);
        const float scale = __expf(m - mnew);
        const float e     = __expf(s - mnew);
        se = se * scale + e;
        st = st * scale + e * tv;
        m  = mnew;
    }

    // merge the 8 groups via LDS
    __shared__ float red_m[GROUPS], red_se[GROUPS], red_st[GROUPS];
    if (lane == 0) { red_m[g] = m; red_se[g] = se; red_st[g] = st; }
    __syncthreads();

    if (t == 0) {
        float M = red_m[0], SE = red_se[0], ST = red_st[0];
        #pragma unroll
        for (int i = 1; i < GROUPS; ++i) {
            const float m2  = red_m[i];
            const float Mn  = fmaxf(M, m2);
            const float s1  = __expf(M - Mn);
            const float s2  = __expf(m2 - Mn);
            SE = SE * s1 + red_se[i] * s2;
            ST = ST * s1 + red_st[i] * s2;
            M  = Mn;
        }
        P[n * CHUNKS + c] = make_float4(M, SE, ST, 0.f);
    }
}

// ---------------------------------------------------------------------------
// Stage 2: merge the CHUNKS partials per n. 1024 threads total.
// ---------------------------------------------------------------------------
__global__ __launch_bounds__(256) void attw_final(
    const float4* __restrict__ P, float* __restrict__ out)
{
    const int n = blockIdx.x * blockDim.x + threadIdx.x;
    if (n >= N_) return;
    const float4* p = P + n * CHUNKS;
    float4 a = p[0];
    float M = a.x, SE = a.y, ST = a.z;
    #pragma unroll
    for (int i = 1; i < CHUNKS; ++i) {
        const float4 b = p[i];
        const float Mn = fmaxf(M, b.x);
        const float s1 = __expf(M - Mn);
        const float s2 = __expf(b.x - Mn);
        SE = SE * s1 + b.y * s2;
        ST = ST * s1 + b.z * s2;
        M  = Mn;
    }
    out[n] = ST / SE;
}

extern "C" void kernel_launch(void* const* d_in, const int* in_sizes, int n_in,
                              void* d_out, int out_size, void* d_ws, size_t ws_size,
                              hipStream_t stream) {
    const float* X = (const float*)d_in[0];  // input_seq [1024,2048,128]
    const float* Z = (const float*)d_in[1];  // cross_input [1024,128]
    const float* W = (const float*)d_in[2];  // W [128,128]
    const float* V = (const float*)d_in[3];  // v [128]
    float* out = (float*)d_out;              // [1024,1] fp32

    // workspace layout: Q [1024*128 floats = 512 KB] | P [1024*8 float4 = 128 KB]
    float*  Q = (float*)d_ws;
    float4* P = (float4*)((char*)d_ws + (size_t)N_ * D_ * sizeof(float));

    attw_q<<<N_, D_, 0, stream>>>(Z, W, Q);
    attw_partial<<<dim3(CHUNKS, N_), THREADS, 0, stream>>>(X, Q, V, P);
    attw_final<<<(N_ + 255) / 256, 256, 0, stream>>>(P, out);
}